// Round 2
// baseline (2790.161 us; speedup 1.0000x reference)
//
#include <hip/hip_runtime.h>

#define F 128

// out = x  (self-loop term), float4-vectorized
__global__ void init_out_kernel(const float* __restrict__ x, float* __restrict__ out, int n4) {
    int i = blockIdx.x * blockDim.x + threadIdx.x;
    int stride = gridDim.x * blockDim.x;
    const float4* x4 = (const float4*)x;
    float4* o4 = (float4*)out;
    for (; i < n4; i += stride) o4[i] = x4[i];
}

// 32 threads per edge; thread c of edge e: float4 gather + 4 atomic adds.
// Work item t in [0, E*32): e = t>>5, chunk c = t&31 covers floats [4c, 4c+4).
__global__ void scatter_kernel(const float* __restrict__ x,
                               const int* __restrict__ src,
                               const int* __restrict__ dst,
                               float* __restrict__ out, int E) {
    long long t = (long long)blockIdx.x * blockDim.x + threadIdx.x;
    int e = (int)(t >> 5);
    if (e >= E) return;
    int c = (int)(t & 31);
    int s = src[e];
    int d = dst[e];
    float4 v = *(const float4*)&x[s * F + c * 4];
    float* o = &out[d * F + c * 4];
    atomicAdd(o + 0, v.x);
    atomicAdd(o + 1, v.y);
    atomicAdd(o + 2, v.z);
    atomicAdd(o + 3, v.w);
}

__global__ void relu_kernel(float* __restrict__ out, int n4) {
    int i = blockIdx.x * blockDim.x + threadIdx.x;
    int stride = gridDim.x * blockDim.x;
    float4* o4 = (float4*)out;
    for (; i < n4; i += stride) {
        float4 v = o4[i];
        v.x = fmaxf(v.x, 0.f); v.y = fmaxf(v.y, 0.f);
        v.z = fmaxf(v.z, 0.f); v.w = fmaxf(v.w, 0.f);
        o4[i] = v;
    }
}

extern "C" void kernel_launch(void* const* d_in, const int* in_sizes, int n_in,
                              void* d_out, int out_size, void* d_ws, size_t ws_size,
                              hipStream_t stream) {
    const float* x  = (const float*)d_in[0];
    const int*   ei = (const int*)d_in[1];     // [2, E] row-major: src row then dst row
    float* out = (float*)d_out;

    int N = in_sizes[0] / F;          // 100000
    int E = in_sizes[1] / 2;          // 1600000
    int n4 = (N * F) / 4;

    init_out_kernel<<<2048, 256, 0, stream>>>(x, out, n4);

    long long work = (long long)E * 32;
    int blocks = (int)((work + 255) / 256);
    scatter_kernel<<<blocks, 256, 0, stream>>>(x, ei, ei + E, out, E);

    relu_kernel<<<2048, 256, 0, stream>>>(out, n4);
}

// Round 3
// 630.748 us; speedup vs baseline: 4.4236x; 4.4236x over previous
//
#include <hip/hip_runtime.h>

#define F 128

// ---- CSR build ----------------------------------------------------------

__global__ void hist_kernel(const int* __restrict__ dst, int* __restrict__ deg, int E) {
    int i = blockIdx.x * blockDim.x + threadIdx.x;
    int stride = gridDim.x * blockDim.x;
    for (; i < E; i += stride) atomicAdd(&deg[dst[i]], 1);
}

// single-block exclusive scan over N elements (N ~ 100k): each of 1024 threads
// owns a contiguous chunk; Hillis-Steele scan of the 1024 partials in LDS.
__global__ void __launch_bounds__(1024)
scan_kernel(const int* __restrict__ deg, int* __restrict__ offs,
            int* __restrict__ cursor, int N) {
    __shared__ int partial[1024];
    int tid = threadIdx.x;
    int chunk = (N + 1023) / 1024;
    int begin = tid * chunk;
    int end = begin + chunk; if (end > N) end = N; if (begin > N) begin = N;
    int sum = 0;
    for (int i = begin; i < end; ++i) sum += deg[i];
    partial[tid] = sum;
    __syncthreads();
    for (int off = 1; off < 1024; off <<= 1) {
        int t = (tid >= off) ? partial[tid - off] : 0;
        __syncthreads();
        partial[tid] += t;
        __syncthreads();
    }
    int run = partial[tid] - sum;   // exclusive prefix of this chunk
    for (int i = begin; i < end; ++i) {
        offs[i] = run;
        cursor[i] = run;
        run += deg[i];
    }
    if (tid == 1023) offs[N] = partial[1023];  // total edge count
}

__global__ void reorder_kernel(const int* __restrict__ src, const int* __restrict__ dst,
                               int* __restrict__ cursor, int* __restrict__ csr_src, int E) {
    int i = blockIdx.x * blockDim.x + threadIdx.x;
    int stride = gridDim.x * blockDim.x;
    for (; i < E; i += stride) {
        int pos = atomicAdd(&cursor[dst[i]], 1);
        csr_src[pos] = src[i];
    }
}

// ---- fused gather + self-loop + relu ------------------------------------
// 32 lanes per node; lane c owns float4 chunk c. acc = x[node] + sum_j x[src_j].
__global__ void gather_kernel(const float* __restrict__ x, const int* __restrict__ offs,
                              const int* __restrict__ csr_src, float* __restrict__ out, int N) {
    int t = blockIdx.x * blockDim.x + threadIdx.x;
    int node = t >> 5;
    if (node >= N) return;
    int c = t & 31;
    const float4* x4 = (const float4*)x;
    float4 acc = x4[node * 32 + c];            // self-loop term
    int b = offs[node], e = offs[node + 1];
    for (int j = b; j < e; ++j) {
        int s = csr_src[j];                    // broadcast read across the 32 lanes
        float4 v = x4[s * 32 + c];
        acc.x += v.x; acc.y += v.y; acc.z += v.z; acc.w += v.w;
    }
    acc.x = fmaxf(acc.x, 0.f); acc.y = fmaxf(acc.y, 0.f);
    acc.z = fmaxf(acc.z, 0.f); acc.w = fmaxf(acc.w, 0.f);
    ((float4*)out)[node * 32 + c] = acc;
}

// ---- launch --------------------------------------------------------------

extern "C" void kernel_launch(void* const* d_in, const int* in_sizes, int n_in,
                              void* d_out, int out_size, void* d_ws, size_t ws_size,
                              hipStream_t stream) {
    const float* x  = (const float*)d_in[0];
    const int*   ei = (const int*)d_in[1];     // [2, E]: src row then dst row
    float* out = (float*)d_out;

    int N = in_sizes[0] / F;          // 100000
    int E = in_sizes[1] / 2;          // 1600000
    const int* src = ei;
    const int* dst = ei + E;

    // workspace layout (ints), 16B-aligned chunks
    char* ws = (char*)d_ws;
    int* deg     = (int*)ws;                         // N
    int* offs    = deg + ((N + 4) & ~3);             // N+1
    int* cursor  = offs + ((N + 1 + 3) & ~3);        // N
    int* csr_src = cursor + ((N + 4) & ~3);          // E

    hipMemsetAsync(deg, 0, (size_t)N * sizeof(int), stream);
    hist_kernel<<<2048, 256, 0, stream>>>(dst, deg, E);
    scan_kernel<<<1, 1024, 0, stream>>>(deg, offs, cursor, N);
    reorder_kernel<<<2048, 256, 0, stream>>>(src, dst, cursor, csr_src, E);

    int threads = N * 32;
    gather_kernel<<<(threads + 255) / 256, 256, 0, stream>>>(x, offs, csr_src, out, N);
}

// Round 4
// 403.179 us; speedup vs baseline: 6.9204x; 1.5644x over previous
//
#include <hip/hip_runtime.h>

#define F 128
#define SCAN_T 256
#define SCAN_ELEMS 8
#define SCAN_CHUNK (SCAN_T * SCAN_ELEMS)   // 2048 elements per block

// ---- CSR build ----------------------------------------------------------

__global__ void hist_kernel(const int* __restrict__ dst, int* __restrict__ deg, int E) {
    int i = blockIdx.x * blockDim.x + threadIdx.x;
    int stride = gridDim.x * blockDim.x;
    for (; i < E; i += stride) atomicAdd(&deg[dst[i]], 1);
}

// level 1: per-block partial sums over 2048-element chunks
__global__ void scan_partial(const int* __restrict__ deg, int* __restrict__ bsum, int N) {
    int base = blockIdx.x * SCAN_CHUNK + threadIdx.x * SCAN_ELEMS;
    int s = 0;
#pragma unroll
    for (int k = 0; k < SCAN_ELEMS; ++k) {
        int i = base + k;
        if (i < N) s += deg[i];
    }
    for (int off = 32; off; off >>= 1) s += __shfl_down(s, off);
    __shared__ int wt[4];
    int wid = threadIdx.x >> 6;
    if ((threadIdx.x & 63) == 0) wt[wid] = s;
    __syncthreads();
    if (threadIdx.x == 0) bsum[blockIdx.x] = wt[0] + wt[1] + wt[2] + wt[3];
}

// level 2: one wave scans the <=64 block sums
__global__ void scan_bsums(const int* __restrict__ bsum, int* __restrict__ bpref,
                           int* __restrict__ offs, int nB, int N) {
    int t = threadIdx.x;                      // 64 lanes
    int v = (t < nB) ? bsum[t] : 0;
    int inc = v;
    for (int off = 1; off < 64; off <<= 1) {
        int u = __shfl_up(inc, off);
        if (t >= off) inc += u;
    }
    if (t < nB) bpref[t] = inc - v;           // exclusive
    if (t == nB - 1) offs[N] = inc;           // total
}

// level 3: block-local scan + block offset, write offs & cursor
__global__ void scan_write(const int* __restrict__ deg, const int* __restrict__ bpref,
                           int* __restrict__ offs, int* __restrict__ cursor, int N) {
    int tid = threadIdx.x;
    int base = blockIdx.x * SCAN_CHUNK + tid * SCAN_ELEMS;
    int v[SCAN_ELEMS];
    int s = 0;
#pragma unroll
    for (int k = 0; k < SCAN_ELEMS; ++k) {
        int i = base + k;
        v[k] = (i < N) ? deg[i] : 0;
        s += v[k];
    }
    int inc = s;
    int lane = tid & 63, wid = tid >> 6;
    for (int off = 1; off < 64; off <<= 1) {
        int u = __shfl_up(inc, off);
        if (lane >= off) inc += u;
    }
    __shared__ int wt[4];
    if (lane == 63) wt[wid] = inc;
    __syncthreads();
    int wbase = 0;
    for (int w = 0; w < wid; ++w) wbase += wt[w];
    int run = bpref[blockIdx.x] + wbase + (inc - s);   // thread-exclusive prefix
#pragma unroll
    for (int k = 0; k < SCAN_ELEMS; ++k) {
        int i = base + k;
        if (i < N) {
            offs[i] = run;
            cursor[i] = run;
            run += v[k];
        }
    }
}

__global__ void reorder_kernel(const int* __restrict__ src, const int* __restrict__ dst,
                               int* __restrict__ cursor, int* __restrict__ csr_src, int E) {
    int i = blockIdx.x * blockDim.x + threadIdx.x;
    int stride = gridDim.x * blockDim.x;
    for (; i < E; i += stride) {
        int pos = atomicAdd(&cursor[dst[i]], 1);
        csr_src[pos] = src[i];
    }
}

// ---- fused gather + self-loop + relu ------------------------------------
// 32 lanes per node; lane c owns float4 chunk c. acc = x[node] + sum_j x[src_j].
__global__ void gather_kernel(const float* __restrict__ x, const int* __restrict__ offs,
                              const int* __restrict__ csr_src, float* __restrict__ out, int N) {
    int t = blockIdx.x * blockDim.x + threadIdx.x;
    int node = t >> 5;
    if (node >= N) return;
    int c = t & 31;
    const float4* x4 = (const float4*)x;
    float4 acc = x4[node * 32 + c];            // self-loop term
    int b = offs[node], e = offs[node + 1];
    for (int j = b; j < e; ++j) {
        int s = csr_src[j];                    // broadcast read across the 32 lanes
        float4 v = x4[s * 32 + c];
        acc.x += v.x; acc.y += v.y; acc.z += v.z; acc.w += v.w;
    }
    acc.x = fmaxf(acc.x, 0.f); acc.y = fmaxf(acc.y, 0.f);
    acc.z = fmaxf(acc.z, 0.f); acc.w = fmaxf(acc.w, 0.f);
    ((float4*)out)[node * 32 + c] = acc;
}

// ---- launch --------------------------------------------------------------

extern "C" void kernel_launch(void* const* d_in, const int* in_sizes, int n_in,
                              void* d_out, int out_size, void* d_ws, size_t ws_size,
                              hipStream_t stream) {
    const float* x  = (const float*)d_in[0];
    const int*   ei = (const int*)d_in[1];     // [2, E]: src row then dst row
    float* out = (float*)d_out;

    int N = in_sizes[0] / F;          // 100000
    int E = in_sizes[1] / 2;          // 1600000
    const int* src = ei;
    const int* dst = ei + E;

    // workspace layout (ints), 16B-aligned chunks
    char* ws = (char*)d_ws;
    int* deg     = (int*)ws;                         // N
    int* offs    = deg + ((N + 4) & ~3);             // N+1
    int* cursor  = offs + ((N + 1 + 3) & ~3);        // N
    int* csr_src = cursor + ((N + 4) & ~3);          // E
    int* bsum    = csr_src + ((E + 3) & ~3);         // <=64
    int* bpref   = bsum + 64;                        // <=64

    int nB = (N + SCAN_CHUNK - 1) / SCAN_CHUNK;      // 49 for N=100000 (<=64 required)

    hipMemsetAsync(deg, 0, (size_t)N * sizeof(int), stream);
    hist_kernel<<<2048, 256, 0, stream>>>(dst, deg, E);
    scan_partial<<<nB, SCAN_T, 0, stream>>>(deg, bsum, N);
    scan_bsums<<<1, 64, 0, stream>>>(bsum, bpref, offs, nB, N);
    scan_write<<<nB, SCAN_T, 0, stream>>>(deg, bpref, offs, cursor, N);
    reorder_kernel<<<2048, 256, 0, stream>>>(src, dst, cursor, csr_src, E);

    int threads = N * 32;
    gather_kernel<<<(threads + 255) / 256, 256, 0, stream>>>(x, offs, csr_src, out, N);
}

// Round 5
// 307.717 us; speedup vs baseline: 9.0673x; 1.3102x over previous
//
#include <hip/hip_runtime.h>

#define F 128
#define SCAN_T 256
#define SCAN_ELEMS 8
#define SCAN_CHUNK (SCAN_T * SCAN_ELEMS)   // 2048 elements per block

// ---- pass 1: histogram + per-edge rank (one atomic pass) -----------------
__global__ void hist_rank_kernel(const int* __restrict__ dst, int* __restrict__ deg,
                                 int* __restrict__ rank, int E) {
    int i = (blockIdx.x * blockDim.x + threadIdx.x) * 4;
    if (i + 3 < E) {
        int4 d = *(const int4*)&dst[i];
        int4 r;
        r.x = atomicAdd(&deg[d.x], 1);
        r.y = atomicAdd(&deg[d.y], 1);
        r.z = atomicAdd(&deg[d.z], 1);
        r.w = atomicAdd(&deg[d.w], 1);
        *(int4*)&rank[i] = r;
    } else {
        for (int k = i; k < E; ++k) rank[k] = atomicAdd(&deg[dst[k]], 1);
    }
}

// fallback (small-ws): histogram only
__global__ void hist_kernel(const int* __restrict__ dst, int* __restrict__ deg, int E) {
    int i = (blockIdx.x * blockDim.x + threadIdx.x) * 4;
    if (i + 3 < E) {
        int4 d = *(const int4*)&dst[i];
        atomicAdd(&deg[d.x], 1); atomicAdd(&deg[d.y], 1);
        atomicAdd(&deg[d.z], 1); atomicAdd(&deg[d.w], 1);
    } else {
        for (int k = i; k < E; ++k) atomicAdd(&deg[dst[k]], 1);
    }
}

// ---- 3-level scan --------------------------------------------------------
__global__ void scan_partial(const int* __restrict__ deg, int* __restrict__ bsum, int N) {
    int base = blockIdx.x * SCAN_CHUNK + threadIdx.x * SCAN_ELEMS;
    int s = 0;
#pragma unroll
    for (int k = 0; k < SCAN_ELEMS; ++k) {
        int i = base + k;
        if (i < N) s += deg[i];
    }
    for (int off = 32; off; off >>= 1) s += __shfl_down(s, off);
    __shared__ int wt[4];
    int wid = threadIdx.x >> 6;
    if ((threadIdx.x & 63) == 0) wt[wid] = s;
    __syncthreads();
    if (threadIdx.x == 0) bsum[blockIdx.x] = wt[0] + wt[1] + wt[2] + wt[3];
}

__global__ void scan_bsums(const int* __restrict__ bsum, int* __restrict__ bpref,
                           int* __restrict__ offs, int nB, int N) {
    int t = threadIdx.x;                      // 64 lanes
    int v = (t < nB) ? bsum[t] : 0;
    int inc = v;
    for (int off = 1; off < 64; off <<= 1) {
        int u = __shfl_up(inc, off);
        if (t >= off) inc += u;
    }
    if (t < nB) bpref[t] = inc - v;           // exclusive
    if (t == nB - 1) offs[N] = inc;           // total
}

__global__ void scan_write(const int* __restrict__ deg, const int* __restrict__ bpref,
                           int* __restrict__ offs, int* __restrict__ cursor, int N) {
    int tid = threadIdx.x;
    int base = blockIdx.x * SCAN_CHUNK + tid * SCAN_ELEMS;
    int v[SCAN_ELEMS];
    int s = 0;
#pragma unroll
    for (int k = 0; k < SCAN_ELEMS; ++k) {
        int i = base + k;
        v[k] = (i < N) ? deg[i] : 0;
        s += v[k];
    }
    int inc = s;
    int lane = tid & 63, wid = tid >> 6;
    for (int off = 1; off < 64; off <<= 1) {
        int u = __shfl_up(inc, off);
        if (lane >= off) inc += u;
    }
    __shared__ int wt[4];
    if (lane == 63) wt[wid] = inc;
    __syncthreads();
    int wbase = 0;
    for (int w = 0; w < wid; ++w) wbase += wt[w];
    int run = bpref[blockIdx.x] + wbase + (inc - s);
#pragma unroll
    for (int k = 0; k < SCAN_ELEMS; ++k) {
        int i = base + k;
        if (i < N) {
            offs[i] = run;
            if (cursor) cursor[i] = run;
            run += v[k];
        }
    }
}

// ---- pass 2 (rank path): atomic-free edge placement ----------------------
__global__ void scatter_pos(const int* __restrict__ src, const int* __restrict__ dst,
                            const int* __restrict__ rank, const int* __restrict__ offs,
                            int* __restrict__ csr_src, int E) {
    int i = (blockIdx.x * blockDim.x + threadIdx.x) * 4;
    if (i + 3 < E) {
        int4 s = *(const int4*)&src[i];
        int4 d = *(const int4*)&dst[i];
        int4 r = *(const int4*)&rank[i];
        csr_src[offs[d.x] + r.x] = s.x;
        csr_src[offs[d.y] + r.y] = s.y;
        csr_src[offs[d.z] + r.z] = s.z;
        csr_src[offs[d.w] + r.w] = s.w;
    } else {
        for (int k = i; k < E; ++k) csr_src[offs[dst[k]] + rank[k]] = src[k];
    }
}

// fallback: atomic cursor reorder
__global__ void reorder_kernel(const int* __restrict__ src, const int* __restrict__ dst,
                               int* __restrict__ cursor, int* __restrict__ csr_src, int E) {
    int i = (blockIdx.x * blockDim.x + threadIdx.x) * 4;
    if (i + 3 < E) {
        int4 s = *(const int4*)&src[i];
        int4 d = *(const int4*)&dst[i];
        csr_src[atomicAdd(&cursor[d.x], 1)] = s.x;
        csr_src[atomicAdd(&cursor[d.y], 1)] = s.y;
        csr_src[atomicAdd(&cursor[d.z], 1)] = s.z;
        csr_src[atomicAdd(&cursor[d.w], 1)] = s.w;
    } else {
        for (int k = i; k < E; ++k) csr_src[atomicAdd(&cursor[dst[k]], 1)] = src[k];
    }
}

// ---- fused gather + self-loop + relu, 4x unrolled ------------------------
__global__ void gather_kernel(const float* __restrict__ x, const int* __restrict__ offs,
                              const int* __restrict__ csr_src, float* __restrict__ out, int N) {
    int t = blockIdx.x * blockDim.x + threadIdx.x;
    int node = t >> 5;
    if (node >= N) return;
    int c = t & 31;
    const float4* x4 = (const float4*)x;
    float4 acc = x4[node * 32 + c];            // self-loop term
    int b = offs[node], e = offs[node + 1];
    int j = b;
    for (; j + 3 < e; j += 4) {                // 4 independent row loads in flight
        int s0 = csr_src[j + 0];
        int s1 = csr_src[j + 1];
        int s2 = csr_src[j + 2];
        int s3 = csr_src[j + 3];
        float4 v0 = x4[s0 * 32 + c];
        float4 v1 = x4[s1 * 32 + c];
        float4 v2 = x4[s2 * 32 + c];
        float4 v3 = x4[s3 * 32 + c];
        acc.x += v0.x + v1.x + v2.x + v3.x;
        acc.y += v0.y + v1.y + v2.y + v3.y;
        acc.z += v0.z + v1.z + v2.z + v3.z;
        acc.w += v0.w + v1.w + v2.w + v3.w;
    }
    for (; j < e; ++j) {
        int s = csr_src[j];
        float4 v = x4[s * 32 + c];
        acc.x += v.x; acc.y += v.y; acc.z += v.z; acc.w += v.w;
    }
    acc.x = fmaxf(acc.x, 0.f); acc.y = fmaxf(acc.y, 0.f);
    acc.z = fmaxf(acc.z, 0.f); acc.w = fmaxf(acc.w, 0.f);
    ((float4*)out)[node * 32 + c] = acc;
}

// ---- launch --------------------------------------------------------------
extern "C" void kernel_launch(void* const* d_in, const int* in_sizes, int n_in,
                              void* d_out, int out_size, void* d_ws, size_t ws_size,
                              hipStream_t stream) {
    const float* x  = (const float*)d_in[0];
    const int*   ei = (const int*)d_in[1];     // [2, E]: src row then dst row
    float* out = (float*)d_out;

    int N = in_sizes[0] / F;          // 100000
    int E = in_sizes[1] / 2;          // 1600000
    const int* src = ei;
    const int* dst = ei + E;

    char* ws = (char*)d_ws;
    int* deg     = (int*)ws;                         // N
    int* offs    = deg + ((N + 4) & ~3);             // N+1
    int* csr_src = offs + ((N + 1 + 3) & ~3);        // E
    int* tail    = csr_src + ((E + 3) & ~3);         // rank (E) or cursor (N)
    // rank path needs: tail + E + 128 ints
    size_t need_rank = ((char*)(tail + ((E + 3) & ~3) + 128)) - ws;
    bool use_rank = ws_size >= need_rank;            // launch-constant -> graph-safe

    int* bsum, *bpref;
    if (use_rank) { bsum = tail + ((E + 3) & ~3); }
    else          { bsum = tail + ((N + 4) & ~3); }
    bpref = bsum + 64;

    int nB = (N + SCAN_CHUNK - 1) / SCAN_CHUNK;      // 49 for N=100000
    int eb = (E / 4 + 255) / 256 + 1;                // blocks for 4-wide edge passes

    hipMemsetAsync(deg, 0, (size_t)N * sizeof(int), stream);

    if (use_rank) {
        hist_rank_kernel<<<eb, 256, 0, stream>>>(dst, deg, tail /*rank*/, E);
        scan_partial<<<nB, SCAN_T, 0, stream>>>(deg, bsum, N);
        scan_bsums<<<1, 64, 0, stream>>>(bsum, bpref, offs, nB, N);
        scan_write<<<nB, SCAN_T, 0, stream>>>(deg, bpref, offs, nullptr, N);
        scatter_pos<<<eb, 256, 0, stream>>>(src, dst, tail /*rank*/, offs, csr_src, E);
    } else {
        hist_kernel<<<eb, 256, 0, stream>>>(dst, deg, E);
        scan_partial<<<nB, SCAN_T, 0, stream>>>(deg, bsum, N);
        scan_bsums<<<1, 64, 0, stream>>>(bsum, bpref, offs, nB, N);
        scan_write<<<nB, SCAN_T, 0, stream>>>(deg, bpref, offs, tail /*cursor*/, N);
        reorder_kernel<<<eb, 256, 0, stream>>>(src, dst, tail /*cursor*/, csr_src, E);
    }

    int threads = N * 32;
    gather_kernel<<<(threads + 255) / 256, 256, 0, stream>>>(x, offs, csr_src, out, N);
}